// Round 3
// baseline (1502.884 us; speedup 1.0000x reference)
//
#include <hip/hip_runtime.h>
#include <math.h>

#define NROWS 8192
#define DIN   1536
#define DH    4096
#define DOUT  2048
#define KCB   8192

typedef _Float16 h8 __attribute__((ext_vector_type(8)));
typedef _Float16 h4 __attribute__((ext_vector_type(4)));
typedef float    f4 __attribute__((ext_vector_type(4)));
typedef float    fx16 __attribute__((ext_vector_type(16)));
typedef unsigned int u32;
typedef unsigned long long u64;

// async global->LDS 16B per lane; lds base is wave-uniform, HW adds lane*16
__device__ __forceinline__ void g2l16(const _Float16* g, const char* ldsBase) {
    __builtin_amdgcn_global_load_lds(
        (const __attribute__((address_space(1))) u32*)g,
        (__attribute__((address_space(3))) u32*)ldsBase, 16, 0, 0);
}

__device__ __forceinline__ void bar() {
    asm volatile("" ::: "memory");
    __builtin_amdgcn_s_barrier();
    asm volatile("" ::: "memory");
}
#define WAITLG(N) do { asm volatile("s_waitcnt lgkmcnt(" #N ")" ::: "memory"); \
                       __builtin_amdgcn_sched_barrier(0); } while (0)
#define WAITVM(N) do { asm volatile("s_waitcnt vmcnt(" #N ")" ::: "memory"); \
                       __builtin_amdgcn_sched_barrier(0); } while (0)
#define MFMA32(A, B, C) __builtin_amdgcn_mfma_f32_32x32x16_f16(A, B, C, 0, 0, 0)

// ---------------------------------------------------------------------------
// split fp32 -> (hi fp16, lo fp16*4096) with exact pow2 pre-scale
// ---------------------------------------------------------------------------
__global__ __launch_bounds__(256) void split_scale_kernel(
    const float* __restrict__ src, _Float16* __restrict__ hi,
    _Float16* __restrict__ lo, float scale)
{
    size_t i = ((size_t)blockIdx.x * 256 + threadIdx.x) * 4;
    float4 v = *(const float4*)(src + i);
    float a0 = v.x * scale, a1 = v.y * scale, a2 = v.z * scale, a3 = v.w * scale;
    h4 vh, vl;
    _Float16 h0 = (_Float16)a0; vh[0] = h0; vl[0] = (_Float16)((a0 - (float)h0) * 4096.0f);
    _Float16 h1 = (_Float16)a1; vh[1] = h1; vl[1] = (_Float16)((a1 - (float)h1) * 4096.0f);
    _Float16 h2 = (_Float16)a2; vh[2] = h2; vl[2] = (_Float16)((a2 - (float)h2) * 4096.0f);
    _Float16 h3 = (_Float16)a3; vh[3] = h3; vl[3] = (_Float16)((a3 - (float)h3) * 4096.0f);
    *(h4*)(hi + i) = vh;
    *(h4*)(lo + i) = vl;
}

// ---------------------------------------------------------------------------
// 8-wave 128x256-tile double-buffered GEMM on v_mfma_f32_32x32x16_f16.
//   SPLIT=1: split-fp16 C = A*B^T (+bias*biasScale), 3 MFMA/frag, BK=32.
//   SPLIT=0: plain hi*hi approx-score GEMM -> u8 matrix, BK=64.
// LDS image identical to r2 (rows of 128B = 8x16B slots, XOR slot swizzle,
// 0 bank conflicts verified). 2 phases per K-tile by B n-quad (cols 0..31 /
// 32..63 per wave); ALL 16 ds_reads issued in phase A (n-quad-1's 4 reads
// overlap phase-A MFMA via counted lgkmcnt(4)); phase B is pure MFMA.
// 3 barriers + 1 vmcnt gate per tile:
//   [16 reads][stage s2,s3(t+1)->Ln] bar  lgkm(4) MFMA(nq0)  bar
//   [stage A,A,s0,s1(t+2)->Lc] lgkm(0) MFMA(nq1) WAITVM(4|0) bar
// Hazard proof: phB stages overwrite only A+stripe0/1 rows, whose reads
// drained at phA's lgkm(4) (pre-barrier, all waves). Stripe2/3(t+1) staged in
// phA(t) overwrite rows whose reads drained at phB(t-1)'s lgkm(0), before the
// tile-close barrier. WAITVM(4) at tile close drains exactly t+1's 6 loads
// (outstanding then: [phB(t-1):4(t+1)][phA(t):2(t+1)][phB(t):4(t+2)] -> 4).
// ---------------------------------------------------------------------------
template<int SPLIT>
__global__ __launch_bounds__(512, 2) void gemm32_kernel(
    const _Float16* __restrict__ Ah, const _Float16* __restrict__ Al,
    const _Float16* __restrict__ Bh, const _Float16* __restrict__ Bl,
    const float* __restrict__ bias, float biasScale,
    _Float16* __restrict__ Ch, _Float16* __restrict__ Cl,
    unsigned char* __restrict__ S8, int M, int N, int K)
{
    constexpr int BK = SPLIT ? 32 : 64;       // K-advance per LDS tile
    constexpr int KS = SPLIT ? 2 : 4;         // 16-wide k-slices per tile
    constexpr u32 BUFSZ = 49152;              // 16KB A + 32KB B per buffer
    __shared__ __align__(16) char lds[2 * BUFSZ];

    // T1: bijective XCD swizzle (all grids here are multiples of 8)
    const int nwg = (int)(gridDim.x * gridDim.y);
    int wg = (int)(blockIdx.y * gridDim.x + blockIdx.x);
    int sw = (wg & 7) * (nwg >> 3) + (wg >> 3);
    const int bx = sw % (int)gridDim.x, by = sw / (int)gridDim.x;
    const int bm0 = by * 128, bn0 = bx * 256;

    const int tid = (int)threadIdx.x;
    const int w = tid >> 6, lane = tid & 63;
    const u32 r5 = (u32)(lane & 31), hfl = (u32)(lane >> 5);
    const int wm = (w >> 2) * 64, wn = (w & 3) * 64;

    // staging (pre-swizzled global source, linear LDS dest — rule #21):
    // lane l -> chunk row r8=l>>3, lds slot sl=l&7, source slot s0 = sl^r8
    const int r8 = lane >> 3, sl = lane & 7;
    const int s0 = sl ^ r8;
    const _Float16* PA; const _Float16* PB; int eo;
    if constexpr (SPLIT) {
        PA = (s0 & 4) ? Al : Ah;              // slot bit2 selects hi/lo plane
        PB = (s0 & 4) ? Bl : Bh;
        eo = (s0 & 3) * 8;
    } else {
        PA = Ah; PB = Bh;
        eo = (s0 >> 2) * 32 + (s0 & 3) * 8;   // slot bit2 selects k-subtile
    }
    const _Float16* srcA0 = PA + (size_t)(bm0 + w * 16 + r8) * K + eo;
    const _Float16* srcA1 = srcA0 + (size_t)8 * K;
    const _Float16* srcB0 = PB + (size_t)(bn0 + (w >> 1) * 64 + (w & 1) * 8 + r8) * K + eo;
    const size_t jS = (size_t)16 * K;         // B stripe stride (16 rows)

    // wave-uniform LDS chunk destinations
    const u32 aDst0 = (u32)w * 2048u, aDst1 = aDst0 + 1024u;
    const u32 bDstB = 16384u + (u32)(w >> 1) * 8192u + (u32)(w & 1) * 1024u; // + j*2048

    // ds_read bases: frag (row, slice g=ks*2+hfl, plane p) at byte
    //   row*128 + (((p*4 + g) ^ (row&7)) << 4); lo plane = hi offset ^ 64
    u32 aB[2], aX[2], bB[2], bX[2];
#pragma unroll
    for (int mi = 0; mi < 2; ++mi) {
        u32 row = (u32)wm + (u32)mi * 32u + r5;
        aB[mi] = row * 128u;
        aX[mi] = (row & 7u) << 4;
    }
#pragma unroll
    for (int nq = 0; nq < 2; ++nq) {
        u32 row = (u32)wn + (u32)nq * 32u + r5;
        bB[nq] = 16384u + row * 128u;
        bX[nq] = (row & 7u) << 4;
    }

    fx16 acc[2][2] = {};
    fx16 accx[SPLIT ? 2 : 1][SPLIT ? 2 : 1] = {};

    const int NT = K / BK;

    // prologue: tile0 {A,A,s0,s1,s2,s3}; tile1 {A,A,s0,s1} (s2s3(1) in phA(0))
    {
        char* L0 = lds; char* L1 = lds + BUFSZ;
        g2l16(srcA0, L0 + aDst0);
        g2l16(srcA1, L0 + aDst1);
        g2l16(srcB0,          L0 + bDstB);
        g2l16(srcB0 + jS,     L0 + bDstB + 2048);
        g2l16(srcB0 + 2 * jS, L0 + bDstB + 4096);
        g2l16(srcB0 + 3 * jS, L0 + bDstB + 6144);
        g2l16(srcA0 + BK, L1 + aDst0);
        g2l16(srcA1 + BK, L1 + aDst1);
        g2l16(srcB0 + BK,      L1 + bDstB);
        g2l16(srcB0 + jS + BK, L1 + bDstB + 2048);
        WAITVM(4);   // tile0's 6 landed; tile1's 4 stay in flight
        bar();
    }

    for (int t = 0; t < NT; ++t) {
        char* Lc = lds + ((t & 1) ? BUFSZ : 0u);
        char* Ln = lds + ((t & 1) ? 0u : BUFSZ);
        const bool st1 = (t + 1 < NT), st2 = (t + 2 < NT);
        const size_t k1 = (size_t)(t + 1) * BK;
        const size_t k2 = (size_t)(t + 2) * BK;

        // ---- phase A: read entire tile t; stage s2,s3(t+1) ----
        h8 aH[2][KS], bH[2][KS];
        h8 aL[SPLIT ? 2 : 1][SPLIT ? KS : 1], bL[SPLIT ? 2 : 1][SPLIT ? KS : 1];
#pragma unroll
        for (int mi = 0; mi < 2; ++mi)
#pragma unroll
            for (int ks = 0; ks < KS; ++ks) {
                u32 o = aB[mi] + ((((u32)(ks * 2) + hfl) << 4) ^ aX[mi]);
                aH[mi][ks] = *(const h8*)(Lc + o);
                if constexpr (SPLIT) aL[mi][ks] = *(const h8*)(Lc + (o ^ 64u));
            }
#pragma unroll
        for (int nq = 0; nq < 2; ++nq)
#pragma unroll
            for (int ks = 0; ks < KS; ++ks) {
                u32 o = bB[nq] + ((((u32)(ks * 2) + hfl) << 4) ^ bX[nq]);
                bH[nq][ks] = *(const h8*)(Lc + o);
                if constexpr (SPLIT) bL[nq][ks] = *(const h8*)(Lc + (o ^ 64u));
            }
        if (st1) {
            g2l16(srcB0 + 2 * jS + k1, Ln + bDstB + 4096);
            g2l16(srcB0 + 3 * jS + k1, Ln + bDstB + 6144);
        }
        bar();
        WAITLG(4);                 // a + b-nq0 drained; b-nq1 may stay in flight
        __builtin_amdgcn_s_setprio(1);
        if constexpr (SPLIT) {
#pragma unroll
            for (int ks = 0; ks < 2; ++ks) {
                acc[0][0] = MFMA32(aH[0][ks], bH[0][ks], acc[0][0]);
                acc[1][0] = MFMA32(aH[1][ks], bH[0][ks], acc[1][0]);
            }
#pragma unroll
            for (int ks = 0; ks < 2; ++ks) {
                accx[0][0] = MFMA32(aH[0][ks], bL[0][ks], accx[0][0]);
                accx[1][0] = MFMA32(aH[1][ks], bL[0][ks], accx[1][0]);
            }
#pragma unroll
            for (int ks = 0; ks < 2; ++ks) {
                accx[0][0] = MFMA32(aL[0][ks], bH[0][ks], accx[0][0]);
                accx[1][0] = MFMA32(aL[1][ks], bH[0][ks], accx[1][0]);
            }
        } else {
#pragma unroll
            for (int ks = 0; ks < 4; ++ks) {
                acc[0][0] = MFMA32(aH[0][ks], bH[0][ks], acc[0][0]);
                acc[1][0] = MFMA32(aH[1][ks], bH[0][ks], acc[1][0]);
            }
        }
        __builtin_amdgcn_s_setprio(0);
        bar();

        // ---- phase B: pure MFMA (nq=1); stage A,A,s0,s1(t+2) ----
        if (st2) {
            g2l16(srcA0 + k2, Lc + aDst0);
            g2l16(srcA1 + k2, Lc + aDst1);
            g2l16(srcB0 + k2,      Lc + bDstB);
            g2l16(srcB0 + jS + k2, Lc + bDstB + 2048);
        }
        WAITLG(0);                 // b-nq1 reads (issued ~1 phase ago)
        __builtin_amdgcn_s_setprio(1);
        if constexpr (SPLIT) {
#pragma unroll
            for (int ks = 0; ks < 2; ++ks) {
                acc[0][1] = MFMA32(aH[0][ks], bH[1][ks], acc[0][1]);
                acc[1][1] = MFMA32(aH[1][ks], bH[1][ks], acc[1][1]);
            }
#pragma unroll
            for (int ks = 0; ks < 2; ++ks) {
                accx[0][1] = MFMA32(aH[0][ks], bL[1][ks], accx[0][1]);
                accx[1][1] = MFMA32(aH[1][ks], bL[1][ks], accx[1][1]);
            }
#pragma unroll
            for (int ks = 0; ks < 2; ++ks) {
                accx[0][1] = MFMA32(aL[0][ks], bH[1][ks], accx[0][1]);
                accx[1][1] = MFMA32(aL[1][ks], bH[1][ks], accx[1][1]);
            }
        } else {
#pragma unroll
            for (int ks = 0; ks < 4; ++ks) {
                acc[0][1] = MFMA32(aH[0][ks], bH[1][ks], acc[0][1]);
                acc[1][1] = MFMA32(aH[1][ks], bH[1][ks], acc[1][1]);
            }
        }
        __builtin_amdgcn_s_setprio(0);
        if (st2) { WAITVM(4); } else { WAITVM(0); }
        bar();
    }

    // epilogue: 32x32 C/D layout col = lane&31, row = 4*(lane>>5)+(r&3)+8*(r>>2)
    if constexpr (SPLIT) {
#pragma unroll
        for (int nq = 0; nq < 2; ++nq) {
            int col = bn0 + wn + nq * 32 + (int)r5;
            float bb = bias[col] * biasScale;
#pragma unroll
            for (int mi = 0; mi < 2; ++mi) {
#pragma unroll
                for (int rg = 0; rg < 16; ++rg) {
                    int row = bm0 + wm + mi * 32 + (int)hfl * 4 + (rg & 3) + (rg >> 2) * 8;
                    float v = fmaf(accx[mi][nq][rg], 0.000244140625f, acc[mi][nq][rg]) + bb;
                    _Float16 hi = (_Float16)v;
                    Ch[(size_t)row * N + col] = hi;
                    Cl[(size_t)row * N + col] = (_Float16)((v - (float)hi) * 4096.0f);
                }
            }
        }
    } else {
#pragma unroll
        for (int nq = 0; nq < 2; ++nq) {
            int col = bn0 + wn + nq * 32 + (int)r5;
#pragma unroll
            for (int mi = 0; mi < 2; ++mi) {
#pragma unroll
                for (int rg = 0; rg < 16; ++rg) {
                    int row = bm0 + wm + mi * 32 + (int)hfl * 4 + (rg & 3) + (rg >> 2) * 8;
                    float delta = acc[mi][nq][rg] * -0.000244140625f;
                    float qf = (delta + 0.0768f) * (1.0f / 0.0006f);
                    int qi = (int)(qf + 0.5f);
                    qi = qi < 0 ? 0 : (qi > 255 ? 255 : qi);
                    S8[(size_t)row * N + col] = (unsigned char)qi;
                }
            }
        }
    }
}

// ---------------------------------------------------------------------------
// Pass B: per row (one block): u8 min -> candidates (q <= min+3, cap 128) ->
// exact fp32 rescore score = fl(1536 - 2*dot) -> packed (score,idx) min ->
// copy codebook row to out.
// ---------------------------------------------------------------------------
__global__ __launch_bounds__(256) void select_rescore_kernel(
    const unsigned char* __restrict__ S,
    const _Float16* __restrict__ zh, const _Float16* __restrict__ zl,
    const float* __restrict__ CB, float* __restrict__ out)
{
    const int row = blockIdx.x;
    const int t = threadIdx.x;
    __shared__ float zsh[DOUT];
    __shared__ int cand[128];
    __shared__ int ncand;
    __shared__ u32 mred[4];
    __shared__ float wred[4];
    __shared__ u64 bestsh;

    {
        h8 vh = *(const h8*)(zh + (size_t)row * DOUT + t * 8);
        h8 vl = *(const h8*)(zl + (size_t)row * DOUT + t * 8);
#pragma unroll
        for (int j = 0; j < 8; ++j)
            zsh[t * 8 + j] = fmaf((float)vl[j], 0.000244140625f, (float)vh[j]);
    }
    if (t == 0) ncand = 0;

    const uchar4* sr4 = (const uchar4*)(S + (size_t)row * KCB);
    u32 mn = 255;
    uchar4 loc[8];
#pragma unroll
    for (int i = 0; i < 8; ++i) {
        uchar4 v = sr4[t + i * 256];
        loc[i] = v;
        u32 m0 = v.x < v.y ? v.x : v.y;
        u32 m1 = v.z < v.w ? v.z : v.w;
        m0 = m0 < m1 ? m0 : m1;
        mn = m0 < mn ? m0 : mn;
    }
#pragma unroll
    for (int o = 32; o > 0; o >>= 1) { u32 x = __shfl_down(mn, o, 64); mn = x < mn ? x : mn; }
    if ((t & 63) == 0) mred[t >> 6] = mn;
    __syncthreads();
    u32 qmin = mred[0];
    qmin = mred[1] < qmin ? mred[1] : qmin;
    qmin = mred[2] < qmin ? mred[2] : qmin;
    qmin = mred[3] < qmin ? mred[3] : qmin;
    const u32 thr = qmin + 3;

#pragma unroll
    for (int i = 0; i < 8; ++i) {
        uchar4 v = loc[i];
        int base = (t + i * 256) * 4;
        if (v.x <= thr) { int p = atomicAdd(&ncand, 1); if (p < 128) cand[p] = base; }
        if (v.y <= thr) { int p = atomicAdd(&ncand, 1); if (p < 128) cand[p] = base + 1; }
        if (v.z <= thr) { int p = atomicAdd(&ncand, 1); if (p < 128) cand[p] = base + 2; }
        if (v.w <= thr) { int p = atomicAdd(&ncand, 1); if (p < 128) cand[p] = base + 3; }
    }
    __syncthreads();
    int nc = ncand; nc = nc > 128 ? 128 : nc;

    u64 best = 0xFFFFFFFFFFFFFFFFull;
    for (int c = 0; c < nc; ++c) {
        const int k = cand[c];
        const float* cb = CB + (size_t)k * DOUT;
        float part = 0.f;
        float4 p0 = *(const float4*)(cb + t * 8);
        float4 p1 = *(const float4*)(cb + t * 8 + 4);
        part += zsh[t * 8 + 0] * p0.x; part += zsh[t * 8 + 1] * p0.y;
        part += zsh[t * 8 + 2] * p0.z; part += zsh[t * 8 + 3] * p0.w;
        part += zsh[t * 8 + 4] * p1.x; part += zsh[t * 8 + 5] * p1.y;
        part += zsh[t * 8 + 6] * p1.z; part += zsh[t * 8 + 7] * p1.w;
#pragma unroll
        for (int o = 32; o > 0; o >>= 1) part += __shfl_down(part, o, 64);
        if ((t & 63) == 0) wred[t >> 6] = part;
        __syncthreads();
        if (t == 0) {
            float dot = (wred[0] + wred[1]) + (wred[2] + wred[3]);
            float s = fmaf(dot, -2.0f, 1536.0f);
            u32 u = __float_as_uint(s);
            u = (u & 0x80000000u) ? ~u : (u | 0x80000000u);
            u64 key = ((u64)u << 32) | (u32)k;
            best = key < best ? key : best;
        }
        __syncthreads();
    }
    if (t == 0) bestsh = best;
    __syncthreads();
    const int bidx = (int)(bestsh & 0xFFFFFFFFu);
    const float4* src = (const float4*)(CB + (size_t)bidx * DOUT);
    float4* dst = (float4*)(out + (size_t)row * DOUT);
    dst[t] = src[t];
    dst[t + 256] = src[t + 256];
}

// ---------------------------------------------------------------------------
// LayerNorm (+GELU) on split input (scaled by 64), writes split (scale 1).
// ---------------------------------------------------------------------------
template <int GELU, int DMAX>
__global__ __launch_bounds__(256) void ln_split_kernel(
    _Float16* __restrict__ Xh, _Float16* __restrict__ Xl,
    const float* __restrict__ gg, const float* __restrict__ bb, int D)
{
    constexpr int CH = DMAX / 2048;
    const int row = blockIdx.x;
    _Float16* xh = Xh + (size_t)row * D;
    _Float16* xl = Xl + (size_t)row * D;
    const int t = threadIdx.x;
    __shared__ float sred[4];

    float vals[CH * 8];
    float s = 0.f;
#pragma unroll
    for (int c = 0; c < CH; ++c) {
        h8 vh = *(const h8*)(xh + c * 2048 + t * 8);
        h8 vl = *(const h8*)(xl + c * 2048 + t * 8);
#pragma unroll
        for (int j = 0; j < 8; ++j) {
            float v = fmaf((float)vl[j], 0.000244140625f, (float)vh[j]) * 0.015625f;
            vals[c * 8 + j] = v;
            s += v;
        }
    }
#pragma unroll
    for (int o = 32; o > 0; o >>= 1) s += __shfl_down(s, o, 64);
    if ((t & 63) == 0) sred[t >> 6] = s;
    __syncthreads();
    const float mu = (sred[0] + sred[1] + sred[2] + sred[3]) / (float)D;
    __syncthreads();

    float s2 = 0.f;
#pragma unroll
    for (int i = 0; i < CH * 8; ++i) { float d = vals[i] - mu; s2 += d * d; }
#pragma unroll
    for (int o = 32; o > 0; o >>= 1) s2 += __shfl_down(s2, o, 64);
    if ((t & 63) == 0) sred[t >> 6] = s2;
    __syncthreads();
    const float var = (sred[0] + sred[1] + sred[2] + sred[3]) / (float)D;
    const float inv = 1.0f / sqrtf(var + 1e-5f);

#pragma unroll
    for (int c = 0; c < CH; ++c) {
        int base = c * 2048 + t * 8;
        float4 g0 = *(const float4*)(gg + base);
        float4 g1 = *(const float4*)(gg + base + 4);
        float4 b0 = *(const float4*)(bb + base);
        float4 b1 = *(const float4*)(bb + base + 4);
        float gv[8] = {g0.x, g0.y, g0.z, g0.w, g1.x, g1.y, g1.z, g1.w};
        float bv[8] = {b0.x, b0.y, b0.z, b0.w, b1.x, b1.y, b1.z, b1.w};
        h8 oh, ol;
#pragma unroll
        for (int j = 0; j < 8; ++j) {
            float y = (vals[c * 8 + j] - mu) * inv * gv[j] + bv[j];
            if (GELU) y = 0.5f * y * (1.0f + erff(y * 0.70710678118654752f));
            _Float16 hi = (_Float16)y;
            oh[j] = hi;
            ol[j] = (_Float16)((y - (float)hi) * 4096.0f);
        }
        *(h8*)(xh + base) = oh;
        *(h8*)(xl + base) = ol;
    }
}

extern "C" void kernel_launch(void* const* d_in, const int* in_sizes, int n_in,
                              void* d_out, int out_size, void* d_ws, size_t ws_size,
                              hipStream_t stream)
{
    const float* latents = (const float*)d_in[0];
    const float* W1      = (const float*)d_in[1];
    const float* b1      = (const float*)d_in[2];
    const float* g1      = (const float*)d_in[3];
    const float* be1     = (const float*)d_in[4];
    const float* W2      = (const float*)d_in[5];
    const float* b2      = (const float*)d_in[6];
    const float* g2      = (const float*)d_in[7];
    const float* be2     = (const float*)d_in[8];
    const float* CB      = (const float*)d_in[9];
    float* out = (float*)d_out;

    char* ws = (char*)d_ws;
    // phase 1/2: region A [0, 75.5M): lat+W1 splits; later z split
    _Float16* lath = (_Float16*)(ws + 0);
    _Float16* latl = (_Float16*)(ws + 25165824);
    _Float16* W1h  = (_Float16*)(ws + 50331648);
    _Float16* W1l  = (_Float16*)(ws + 62914560);
    _Float16* zh   = (_Float16*)(ws + 0);
    _Float16* zl   = (_Float16*)(ws + 33554432);
    // region D [75.5M, 209.7M): h split; later CBh/CBl + S8 matrix
    _Float16* hh   = (_Float16*)(ws + 75497472);
    _Float16* hl   = (_Float16*)(ws + 142606336);
    _Float16* CBh  = (_Float16*)(ws + 75497472);
    _Float16* CBl  = (_Float16*)(ws + 109051904);
    unsigned char* S8 = (unsigned char*)(ws + 142606336);   // 8192*8192 = 67.1 MB
    // region B [209.7M, 243.3M): W2 split
    _Float16* W2h  = (_Float16*)(ws + 209715200);
    _Float16* W2l  = (_Float16*)(ws + 226492416);

    dim3 blk(256);
    split_scale_kernel<<<(NROWS * DIN) / 1024, blk, 0, stream>>>(latents, lath, latl, 1.0f);
    split_scale_kernel<<<(DH * DIN) / 1024, blk, 0, stream>>>(W1, W1h, W1l, 64.0f);
    split_scale_kernel<<<(DOUT * DH) / 1024, blk, 0, stream>>>(W2, W2h, W2l, 64.0f);

    gemm32_kernel<1><<<dim3(DH / 256, NROWS / 128), dim3(512), 0, stream>>>(
        lath, latl, W1h, W1l, b1, 64.0f, hh, hl, nullptr, NROWS, DH, DIN);
    ln_split_kernel<1, DH><<<NROWS, blk, 0, stream>>>(hh, hl, g1, be1, DH);

    gemm32_kernel<1><<<dim3(DOUT / 256, NROWS / 128), dim3(512), 0, stream>>>(
        hh, hl, W2h, W2l, b2, 64.0f, zh, zl, nullptr, NROWS, DOUT, DH);

    // CB split into dead h region (after GEMM2 consumed h)
    split_scale_kernel<<<(KCB * DOUT) / 1024, blk, 0, stream>>>(CB, CBh, CBl, 8192.0f);

    ln_split_kernel<0, DOUT><<<NROWS, blk, 0, stream>>>(zh, zl, g2, be2, DOUT);

    // pass A: hh-only approx scores -> u8 matrix (into dead hl region)
    gemm32_kernel<0><<<dim3(KCB / 256, NROWS / 128), dim3(512), 0, stream>>>(
        zh, nullptr, CBh, nullptr, nullptr, 0.0f, nullptr, nullptr, S8, NROWS, KCB, DOUT);

    // pass B: candidate select + exact rescore + gather
    select_rescore_kernel<<<NROWS, blk, 0, stream>>>(S8, zh, zl, CB, out);
}